// Round 3
// baseline (3171.181 us; speedup 1.0000x reference)
//
#include <hip/hip_runtime.h>

typedef unsigned short u16;
typedef unsigned int u32;
typedef unsigned long long u64;
typedef __attribute__((ext_vector_type(8))) short short8;
typedef __attribute__((ext_vector_type(4))) float f32x4;
typedef __attribute__((ext_vector_type(4))) u32 u32x4;

#define RN_ 8388608  // B*T*H
#define MFMA16(a, b, c) __builtin_amdgcn_mfma_f32_16x16x32_bf16(a, b, c, 0, 0, 0)

__device__ __forceinline__ u16 f2bf(float f) {
  union { float f; u32 u; } v; v.f = f;
  u32 r = v.u + 0x7fffu + ((v.u >> 16) & 1u);  // RNE (inputs finite)
  return (u16)(r >> 16);
}
__device__ __forceinline__ float bf2f(u16 h) {
  union { u32 u; float f; } v; v.u = ((u32)h) << 16;
  return v.f;
}
__device__ __forceinline__ u32 pk2(float a, float b) {
  return (u32)f2bf(a) | ((u32)f2bf(b) << 16);
}
// scan column ordering: R = blk*32 + u_local*4 + gate  ->  original g = gate*1024 + blk*8 + u_local
__device__ __forceinline__ int permcol(int R) {
  return (R & 3) * 1024 + ((R >> 5) << 3) + ((R >> 2) & 7);
}
__device__ __forceinline__ float sigm(float x) { return 1.f / (1.f + __expf(-x)); }
__device__ __forceinline__ float tanh_(float x) {
  float e = __expf(2.f * x);
  return 1.f - 2.f / (e + 1.f);
}

// -------- transpose + convert + permute --------
// sel0: Wx l0 -> WxT1 [4096][1024]        (GEMM-1 B operand)
// sel1: Wx l1 -> WcT2 [4096][2048] cols 0..1023
// sel2: Wh l0 -> WhT1 [4096][1024]        (L1 scan weights)
// sel3: Wh l1 -> WcT2 cols 1024..2047    (L2 scan combined weights)
__global__ __launch_bounds__(256) void transpose_convert(
    const float* __restrict__ Wx, const float* __restrict__ Wh,
    u16* __restrict__ WxT1, u16* __restrict__ WhT1, u16* __restrict__ WcT2) {
  __shared__ float lds[64][65];
  const int bid = blockIdx.x, tid = threadIdx.x;
  const int sel = bid >> 10;
  const int tile = bid & 1023;
  const int kt = tile & 15, rt = tile >> 4;  // 16 k-tiles x 64 R-tiles
  const float* src;
  u16* dst;
  int rstride, coff;
  if (sel == 0)      { src = Wx;                              dst = WxT1; rstride = 1024; coff = 0; }
  else if (sel == 1) { src = Wx + (size_t)1024 * 4096;        dst = WcT2; rstride = 2048; coff = 0; }
  else if (sel == 2) { src = Wh;                              dst = WhT1; rstride = 1024; coff = 0; }
  else               { src = Wh + (size_t)1024 * 4096;        dst = WcT2; rstride = 2048; coff = 1024; }
#pragma unroll
  for (int ii = 0; ii < 16; ++ii) {
    int idx = ii * 256 + tid;
    int r = idx >> 6, c = idx & 63;
    int run = c >> 3, u = c & 7;
    int blkLoc = run >> 2, gate = run & 3;
    int g = gate * 1024 + (rt * 2 + blkLoc) * 8 + u;
    lds[r][blkLoc * 32 + u * 4 + gate] = src[(size_t)(kt * 64 + r) * 4096 + g];
  }
  __syncthreads();
#pragma unroll
  for (int ii = 0; ii < 16; ++ii) {
    int idx = ii * 256 + tid;
    int rw = idx >> 6, cw = idx & 63;
    dst[(size_t)(rt * 64 + rw) * rstride + coff + kt * 64 + cw] = f2bf(lds[cw][rw]);
  }
}

// -------- GEMM: xproj(bf16,[8192][4096],cols permuted) = x * WxT1^T + bias --------
__global__ __launch_bounds__(256, 2) void gemm_xproj(
    const float* __restrict__ A, const u16* __restrict__ Bt,
    const float* __restrict__ bias, u16* __restrict__ C) {
  __shared__ __align__(16) u16 As[128 * 64];
  __shared__ __align__(16) u16 Bs[128 * 64];
  const int bid = blockIdx.x, tid = threadIdx.x;
  const int bn = bid & 31, bm = bid >> 5;
  const int lane = tid & 63, wid = tid >> 6;
  const int wm = wid >> 1, wn = wid & 1;
  const int l15 = lane & 15, lq = lane >> 4;
  const int srow = tid >> 2, qd = tid & 3;

  f32x4 acc[4][4];
#pragma unroll
  for (int i = 0; i < 4; ++i)
#pragma unroll
    for (int j = 0; j < 4; ++j) acc[i][j] = (f32x4){0.f, 0.f, 0.f, 0.f};

  const u32 rsw = (u32)((l15 & 7) << 4);

  for (int kt = 0; kt < 16; ++kt) {
    f32x4 av[2][4];
    u32x4 bv[2][2];
#pragma unroll
    for (int rr = 0; rr < 2; ++rr) {
      int row = rr * 64 + srow;
      const f32x4* ap = (const f32x4*)(A + (size_t)(bm * 128 + row) * 1024 + kt * 64 + qd * 16);
#pragma unroll
      for (int i = 0; i < 4; ++i) av[rr][i] = ap[i];
      const u32x4* bp = (const u32x4*)(Bt + (size_t)(bn * 128 + row) * 1024 + kt * 64 + qd * 16);
      bv[rr][0] = bp[0]; bv[rr][1] = bp[1];
    }
    __syncthreads();
#pragma unroll
    for (int rr = 0; rr < 2; ++rr) {
      int row = rr * 64 + srow;
      u32 sw = (u32)((row & 7) << 4);
      int base = row * 128 + qd * 32;
      u32x4 w0, w1;
      w0[0] = pk2(av[rr][0][0], av[rr][0][1]); w0[1] = pk2(av[rr][0][2], av[rr][0][3]);
      w0[2] = pk2(av[rr][1][0], av[rr][1][1]); w0[3] = pk2(av[rr][1][2], av[rr][1][3]);
      w1[0] = pk2(av[rr][2][0], av[rr][2][1]); w1[1] = pk2(av[rr][2][2], av[rr][2][3]);
      w1[2] = pk2(av[rr][3][0], av[rr][3][1]); w1[3] = pk2(av[rr][3][2], av[rr][3][3]);
      *(u32x4*)((char*)As + ((base) ^ sw)) = w0;
      *(u32x4*)((char*)As + ((base + 16) ^ sw)) = w1;
      *(u32x4*)((char*)Bs + ((base) ^ sw)) = bv[rr][0];
      *(u32x4*)((char*)Bs + ((base + 16) ^ sw)) = bv[rr][1];
    }
    __syncthreads();
#pragma unroll
    for (int k2 = 0; k2 < 2; ++k2) {
      short8 af[4], bf[4];
#pragma unroll
      for (int f = 0; f < 4; ++f) {
        af[f] = *(const short8*)((const char*)As +
                 (((wm * 64 + f * 16 + l15) * 128 + k2 * 64 + lq * 16) ^ rsw));
        bf[f] = *(const short8*)((const char*)Bs +
                 (((wn * 64 + f * 16 + l15) * 128 + k2 * 64 + lq * 16) ^ rsw));
      }
#pragma unroll
      for (int fi = 0; fi < 4; ++fi)
#pragma unroll
        for (int fj = 0; fj < 4; ++fj)
          acc[fi][fj] = MFMA16(af[fi], bf[fj], acc[fi][fj]);
    }
  }
#pragma unroll
  for (int fj = 0; fj < 4; ++fj) {
    int gc = bn * 128 + wn * 64 + fj * 16 + l15;
    float bvv = bias[permcol(gc)];
#pragma unroll
    for (int fi = 0; fi < 4; ++fi) {
      int gr0 = bm * 128 + wm * 64 + fi * 16 + lq * 4;
#pragma unroll
      for (int r = 0; r < 4; ++r)
        C[(size_t)(gr0 + r) * 4096 + gc] = f2bf(acc[fi][fj][r] + bvv);
    }
  }
}

// -------- fused 2-layer persistent scan --------
// 256 blocks: blk<128 = layer1 (K=1024, weights WhT1), blk>=128 = layer2
// (K=2048 combined [Wx2;Wh2] against [out1(t); h2(t-1)]).
// hpub1: 4 slots x 64KB (t&3); hpub2: 2 slots x 64KB (t&1). Layout [k>>3][b] x 16B.
// flags[0..127]=L1 steps published, flags[128..255]=L2.
// Publishes go sc0/sc1 (write-through, L3-visible); consumers poll flags uncached,
// then acquire-fence (L1+L2 invalidate) and read h with PLAIN CACHED loads so
// co-XCD blocks share the L2 fill instead of each paying the L3 round trip.
template <int LAYER>
__device__ __forceinline__ void scan_body(
    f32x4* partv, float* out_stage, u16* h_stage, int blk2,
    const u16* __restrict__ xproj, const u16* __restrict__ Wt,
    const float* __restrict__ bias2, const int* __restrict__ lengths,
    u64* hpub1, u64* hpub2, int* flags,
    float* __restrict__ outp, float* __restrict__ csf, float* __restrict__ hsf) {
  const int tid = threadIdx.x;
  const int lane = tid & 63, w = tid >> 6;
  const int l15 = lane & 15, q = lane >> 4;
  const int b = (w & 1) * 16 + l15;
  const int u_local = (w >> 1) * 4 + q;
  const int len = lengths[b];

  constexpr int NKS = LAYER ? 16 : 8;
  constexpr int KSTRIDE = LAYER ? 2048 : 1024;
  const int wk = w * (LAYER ? 512 : 256);

  short8 afr[2][NKS];
#pragma unroll
  for (int tt = 0; tt < 2; ++tt)
#pragma unroll
    for (int ks = 0; ks < NKS; ++ks)
      afr[tt][ks] = *(const short8*)(Wt + (size_t)(blk2 * 32 + tt * 16 + l15) * KSTRIDE +
                                     wk + ks * 32 + q * 8);

  float bg0 = 0.f, bg1 = 0.f, bg2 = 0.f, bg3 = 0.f;
  if (LAYER) {
    bg0 = bias2[permcol(blk2 * 32 + u_local * 4 + 0)];
    bg1 = bias2[permcol(blk2 * 32 + u_local * 4 + 1)];
    bg2 = bias2[permcol(blk2 * 32 + u_local * 4 + 2)];
    bg3 = bias2[permcol(blk2 * 32 + u_local * 4 + 3)];
  }

  f32x4 acc[2][2];
#pragma unroll
  for (int tt = 0; tt < 2; ++tt)
#pragma unroll
    for (int bc = 0; bc < 2; ++bc) acc[tt][bc] = (f32x4){0.f, 0.f, 0.f, 0.f};
  float c = 0.f, h = 0.f;

  for (int t = 0; t < 256; ++t) {
    u64 xp = 0;
    if (!LAYER)
      xp = *(const u64*)(xproj + ((size_t)b * 256 + t) * 4096 + blk2 * 32 + u_local * 4);

    // ---- wave0 polls all 256 flags (uncached), acquire-fence, barrier ----
    if (w == 0) {
      const int n1 = LAYER ? t + 1 : t;       // flag1 threshold
      const int n2 = LAYER ? t : t - 3;       // flag2 threshold (slot reuse / h2 avail)
      if (n1 > 0 || n2 > 0) {
        const int thr = (lane < 32) ? n1 : n2;
        const u32x4* fp = (const u32x4*)flags + lane;
        while (1) {
          u32x4 fv;
          asm volatile("global_load_dwordx4 %0, %1, off sc0 sc1"
                       : "=v"(fv) : "v"(fp) : "memory");
          asm volatile("s_waitcnt vmcnt(0)" ::: "memory");
          bool ok = (int)fv[0] >= thr && (int)fv[1] >= thr &&
                    (int)fv[2] >= thr && (int)fv[3] >= thr;
          if (__all(ok)) break;
          __builtin_amdgcn_s_sleep(1);
        }
        // make everything published-before-those-flags visible to cached loads
        __builtin_amdgcn_fence(__ATOMIC_ACQUIRE, "agent");
      }
    }
    __syncthreads();  // BP: flags satisfied + caches invalidated for whole block

    // ---- load h fragments (plain cached loads), MFMA ----
    if (!LAYER) {
      if (t > 0) {
        const char* hp = (const char*)(hpub1 + (size_t)((t - 1) & 3) * 8192);
        short8 bfv[16];
#pragma unroll
        for (int i = 0; i < 16; ++i) {
          const int ks = i >> 1, bc = i & 1;
          bfv[i] = *(const short8*)(hp + (((w * 32 + ks * 4 + q) * 32 + bc * 16 + l15) << 4));
        }
#pragma unroll
        for (int i = 0; i < 16; ++i) {
          const int ks = i >> 1, bc = i & 1;
          acc[0][bc] = MFMA16(afr[0][ks], bfv[i], acc[0][bc]);
          acc[1][bc] = MFMA16(afr[1][ks], bfv[i], acc[1][bc]);
        }
      }
    } else {
      const char* hp;
      int kb;
      if (w < 2) { hp = (const char*)(hpub1 + (size_t)(t & 3) * 8192); kb = w * 64; }
      else       { hp = (const char*)(hpub2 + (size_t)((t - 1) & 1) * 8192); kb = (w - 2) * 64; }
      if (w < 2 || t > 0) {
#pragma unroll
        for (int g = 0; g < 2; ++g) {   // 2 groups of 16 frags (VGPR cap)
          short8 bfv[16];
#pragma unroll
          for (int i = 0; i < 16; ++i) {
            const int ks = g * 8 + (i >> 1), bc = i & 1;
            bfv[i] = *(const short8*)(hp + (((kb + ks * 4 + q) * 32 + bc * 16 + l15) << 4));
          }
#pragma unroll
          for (int i = 0; i < 16; ++i) {
            const int ks = g * 8 + (i >> 1), bc = i & 1;
            acc[0][bc] = MFMA16(afr[0][ks], bfv[i], acc[0][bc]);
            acc[1][bc] = MFMA16(afr[1][ks], bfv[i], acc[1][bc]);
          }
        }
      }
    }

    // ---- cross-wave K reduction ----
#pragma unroll
    for (int tt = 0; tt < 2; ++tt)
#pragma unroll
      for (int bc = 0; bc < 2; ++bc) {
        partv[(w * 4 + tt * 2 + bc) * 64 + lane] = acc[tt][bc];
        acc[tt][bc] = (f32x4){0.f, 0.f, 0.f, 0.f};
      }
    __syncthreads();  // B1
    f32x4 s = (f32x4){0.f, 0.f, 0.f, 0.f};
#pragma unroll
    for (int w2 = 0; w2 < 4; ++w2) s += partv[(w2 * 4 + w) * 64 + lane];

    float zi, zj, zf, zo;
    if (!LAYER) {
      zi = s[0] + bf2f((u16)(xp & 0xffffu));
      zj = s[1] + bf2f((u16)((xp >> 16) & 0xffffu));
      zf = s[2] + bf2f((u16)((xp >> 32) & 0xffffu)) + 1.f;
      zo = s[3] + bf2f((u16)(xp >> 48));
    } else {
      zi = s[0] + bg0;
      zj = s[1] + bg1;
      zf = s[2] + bg2 + 1.f;
      zo = s[3] + bg3;
    }
    float cn = sigm(zf) * c + sigm(zi) * tanh_(zj);
    float hn = sigm(zo) * tanh_(cn);
    bool mk = t < len;
    c = mk ? cn : c;
    h = mk ? hn : h;
    float ov = mk ? hn : 0.f;
    h_stage[b * 8 + u_local] = f2bf(ov);
    if (LAYER) out_stage[b * 8 + u_local] = ov;
    __syncthreads();  // B2

    // ---- publish h + flag (uncached, L3-visible) ----
    if (tid < 32) {
      u64* hd = LAYER ? (hpub2 + (size_t)(t & 1) * 8192)
                      : (hpub1 + (size_t)(t & 3) * 8192);
      const u64* hsrc = (const u64*)h_stage;
      u64 v0 = hsrc[tid * 2], v1 = hsrc[tid * 2 + 1];
      __hip_atomic_store(hd + (blk2 * 32 + tid) * 2, v0, __ATOMIC_RELAXED,
                         __HIP_MEMORY_SCOPE_AGENT);
      __hip_atomic_store(hd + (blk2 * 32 + tid) * 2 + 1, v1, __ATOMIC_RELAXED,
                         __HIP_MEMORY_SCOPE_AGENT);
    }
    asm volatile("s_waitcnt vmcnt(0)" ::: "memory");  // h visible before flag
    if (tid == 0)
      __hip_atomic_store(flags + LAYER * 128 + blk2, t + 1, __ATOMIC_RELAXED,
                         __HIP_MEMORY_SCOPE_AGENT);
    if (LAYER && tid < 32) {  // per-step rnnout store (layer-2 only)
      const f32x4* osrc = (const f32x4*)out_stage;
      f32x4 o0 = osrc[tid * 2], o1 = osrc[tid * 2 + 1];
      f32x4* od = (f32x4*)(outp + ((size_t)tid * 256 + t) * 1024 + blk2 * 8);
      od[0] = o0; od[1] = o1;
    }
  }
  csf[LAYER * 32768 + b * 1024 + blk2 * 8 + u_local] = c;
  hsf[LAYER * 32768 + b * 1024 + blk2 * 8 + u_local] = h;
}

__global__ __launch_bounds__(256, 2) void lstm_fused(
    const u16* __restrict__ xproj, const u16* __restrict__ WhT1,
    const u16* __restrict__ WcT2, const float* __restrict__ bias2,
    const int* __restrict__ lengths, u64* hpub1, u64* hpub2, int* flags,
    float* __restrict__ outp, float* __restrict__ csf, float* __restrict__ hsf) {
  __shared__ f32x4 partv[16 * 64];
  __shared__ __align__(16) float out_stage[256];
  __shared__ __align__(16) u16 h_stage[256];
  const int blk = blockIdx.x;
  if (blk < 128)
    scan_body<0>(partv, out_stage, h_stage, blk, xproj, WhT1, bias2, lengths,
                 hpub1, hpub2, flags, outp, csf, hsf);
  else
    scan_body<1>(partv, out_stage, h_stage, blk - 128, xproj, WcT2, bias2, lengths,
                 hpub1, hpub2, flags, outp, csf, hsf);
}

// -------- workspace layout --------
#define WS_XPROJ 0u
#define WS_WXT1 (64u << 20)
#define WS_WHT1 (72u << 20)
#define WS_WCT2 (80u << 20)
#define WS_HPUB1 (96u << 20)                       // 4 x 64KB
#define WS_HPUB2 ((96u << 20) + (256u << 10))      // 2 x 64KB
#define WS_FLAGS ((96u << 20) + (384u << 10))      // 256 ints

extern "C" void kernel_launch(void* const* d_in, const int* in_sizes, int n_in,
                              void* d_out, int out_size, void* d_ws, size_t ws_size,
                              hipStream_t stream) {
  const float* x = (const float*)d_in[0];
  const int* lengths = (const int*)d_in[1];
  const float* Wx = (const float*)d_in[2];
  const float* Wh = (const float*)d_in[3];
  const float* bias = (const float*)d_in[4];
  float* outp = (float*)d_out;

  if (ws_size < (size_t)WS_FLAGS + 4096) return;  // fail loudly (output stays poison)

  char* ws = (char*)d_ws;
  u16* xproj = (u16*)(ws + WS_XPROJ);
  u16* WxT1 = (u16*)(ws + WS_WXT1);
  u16* WhT1 = (u16*)(ws + WS_WHT1);
  u16* WcT2 = (u16*)(ws + WS_WCT2);
  u64* hpub1 = (u64*)(ws + WS_HPUB1);
  u64* hpub2 = (u64*)(ws + WS_HPUB2);
  int* flags = (int*)(ws + WS_FLAGS);

  hipMemsetAsync(flags, 0, 256 * sizeof(int), stream);
  transpose_convert<<<4096, 256, 0, stream>>>(Wx, Wh, WxT1, WhT1, WcT2);

  float* cs = outp + RN_;
  float* hs = cs + 65536;

  gemm_xproj<<<2048, 256, 0, stream>>>(x, WxT1, bias, xproj);
  lstm_fused<<<256, 256, 0, stream>>>(xproj, WhT1, WcT2, bias + 4096, lengths,
                                      hpub1, hpub2, flags, outp, cs, hs);
}

// Round 4
// 2452.366 us; speedup vs baseline: 1.2931x; 1.2931x over previous
//
#include <hip/hip_runtime.h>

typedef unsigned short u16;
typedef unsigned int u32;
typedef unsigned long long u64;
typedef __attribute__((ext_vector_type(8))) short short8;
typedef __attribute__((ext_vector_type(4))) float f32x4;
typedef __attribute__((ext_vector_type(4))) u32 u32x4;

#define RN_ 8388608  // B*T*H
#define MFMA16(a, b, c) __builtin_amdgcn_mfma_f32_16x16x32_bf16(a, b, c, 0, 0, 0)

__device__ __forceinline__ u16 f2bf(float f) {
  union { float f; u32 u; } v; v.f = f;
  u32 r = v.u + 0x7fffu + ((v.u >> 16) & 1u);  // RNE (inputs finite)
  return (u16)(r >> 16);
}
__device__ __forceinline__ float bf2f(u16 h) {
  union { u32 u; float f; } v; v.u = ((u32)h) << 16;
  return v.f;
}
__device__ __forceinline__ u32 pk2(float a, float b) {
  return (u32)f2bf(a) | ((u32)f2bf(b) << 16);
}
// scan column ordering: R = blk*32 + u_local*4 + gate  ->  original g = gate*1024 + blk*8 + u_local
__device__ __forceinline__ int permcol(int R) {
  return (R & 3) * 1024 + ((R >> 5) << 3) + ((R >> 2) & 7);
}
__device__ __forceinline__ float sigm(float x) { return 1.f / (1.f + __expf(-x)); }
__device__ __forceinline__ float tanh_(float x) {
  float e = __expf(2.f * x);
  return 1.f - 2.f / (e + 1.f);
}

// -------- transpose + convert + permute --------
// sel0: Wx l0 -> WxT1 [4096][1024]        (GEMM-1 B operand)
// sel1: Wx l1 -> WcT2 [4096][2048] cols 0..1023
// sel2: Wh l0 -> WhT1 [4096][1024]        (L1 scan weights)
// sel3: Wh l1 -> WcT2 cols 1024..2047    (L2 scan combined weights)
__global__ __launch_bounds__(256) void transpose_convert(
    const float* __restrict__ Wx, const float* __restrict__ Wh,
    u16* __restrict__ WxT1, u16* __restrict__ WhT1, u16* __restrict__ WcT2) {
  __shared__ float lds[64][65];
  const int bid = blockIdx.x, tid = threadIdx.x;
  const int sel = bid >> 10;
  const int tile = bid & 1023;
  const int kt = tile & 15, rt = tile >> 4;  // 16 k-tiles x 64 R-tiles
  const float* src;
  u16* dst;
  int rstride, coff;
  if (sel == 0)      { src = Wx;                              dst = WxT1; rstride = 1024; coff = 0; }
  else if (sel == 1) { src = Wx + (size_t)1024 * 4096;        dst = WcT2; rstride = 2048; coff = 0; }
  else if (sel == 2) { src = Wh;                              dst = WhT1; rstride = 1024; coff = 0; }
  else               { src = Wh + (size_t)1024 * 4096;        dst = WcT2; rstride = 2048; coff = 1024; }
#pragma unroll
  for (int ii = 0; ii < 16; ++ii) {
    int idx = ii * 256 + tid;
    int r = idx >> 6, c = idx & 63;
    int run = c >> 3, u = c & 7;
    int blkLoc = run >> 2, gate = run & 3;
    int g = gate * 1024 + (rt * 2 + blkLoc) * 8 + u;
    lds[r][blkLoc * 32 + u * 4 + gate] = src[(size_t)(kt * 64 + r) * 4096 + g];
  }
  __syncthreads();
#pragma unroll
  for (int ii = 0; ii < 16; ++ii) {
    int idx = ii * 256 + tid;
    int rw = idx >> 6, cw = idx & 63;
    dst[(size_t)(rt * 64 + rw) * rstride + coff + kt * 64 + cw] = f2bf(lds[cw][rw]);
  }
}

// -------- GEMM: xproj(bf16,[8192][4096],cols permuted) = x * WxT1^T + bias --------
__global__ __launch_bounds__(256, 2) void gemm_xproj(
    const float* __restrict__ A, const u16* __restrict__ Bt,
    const float* __restrict__ bias, u16* __restrict__ C) {
  __shared__ __align__(16) u16 As[128 * 64];
  __shared__ __align__(16) u16 Bs[128 * 64];
  const int bid = blockIdx.x, tid = threadIdx.x;
  const int bn = bid & 31, bm = bid >> 5;
  const int lane = tid & 63, wid = tid >> 6;
  const int wm = wid >> 1, wn = wid & 1;
  const int l15 = lane & 15, lq = lane >> 4;
  const int srow = tid >> 2, qd = tid & 3;

  f32x4 acc[4][4];
#pragma unroll
  for (int i = 0; i < 4; ++i)
#pragma unroll
    for (int j = 0; j < 4; ++j) acc[i][j] = (f32x4){0.f, 0.f, 0.f, 0.f};

  const u32 rsw = (u32)((l15 & 7) << 4);

  for (int kt = 0; kt < 16; ++kt) {
    f32x4 av[2][4];
    u32x4 bv[2][2];
#pragma unroll
    for (int rr = 0; rr < 2; ++rr) {
      int row = rr * 64 + srow;
      const f32x4* ap = (const f32x4*)(A + (size_t)(bm * 128 + row) * 1024 + kt * 64 + qd * 16);
#pragma unroll
      for (int i = 0; i < 4; ++i) av[rr][i] = ap[i];
      const u32x4* bp = (const u32x4*)(Bt + (size_t)(bn * 128 + row) * 1024 + kt * 64 + qd * 16);
      bv[rr][0] = bp[0]; bv[rr][1] = bp[1];
    }
    __syncthreads();
#pragma unroll
    for (int rr = 0; rr < 2; ++rr) {
      int row = rr * 64 + srow;
      u32 sw = (u32)((row & 7) << 4);
      int base = row * 128 + qd * 32;
      u32x4 w0, w1;
      w0[0] = pk2(av[rr][0][0], av[rr][0][1]); w0[1] = pk2(av[rr][0][2], av[rr][0][3]);
      w0[2] = pk2(av[rr][1][0], av[rr][1][1]); w0[3] = pk2(av[rr][1][2], av[rr][1][3]);
      w1[0] = pk2(av[rr][2][0], av[rr][2][1]); w1[1] = pk2(av[rr][2][2], av[rr][2][3]);
      w1[2] = pk2(av[rr][3][0], av[rr][3][1]); w1[3] = pk2(av[rr][3][2], av[rr][3][3]);
      *(u32x4*)((char*)As + ((base) ^ sw)) = w0;
      *(u32x4*)((char*)As + ((base + 16) ^ sw)) = w1;
      *(u32x4*)((char*)Bs + ((base) ^ sw)) = bv[rr][0];
      *(u32x4*)((char*)Bs + ((base + 16) ^ sw)) = bv[rr][1];
    }
    __syncthreads();
#pragma unroll
    for (int k2 = 0; k2 < 2; ++k2) {
      short8 af[4], bf[4];
#pragma unroll
      for (int f = 0; f < 4; ++f) {
        af[f] = *(const short8*)((const char*)As +
                 (((wm * 64 + f * 16 + l15) * 128 + k2 * 64 + lq * 16) ^ rsw));
        bf[f] = *(const short8*)((const char*)Bs +
                 (((wn * 64 + f * 16 + l15) * 128 + k2 * 64 + lq * 16) ^ rsw));
      }
#pragma unroll
      for (int fi = 0; fi < 4; ++fi)
#pragma unroll
        for (int fj = 0; fj < 4; ++fj)
          acc[fi][fj] = MFMA16(af[fi], bf[fj], acc[fi][fj]);
    }
  }
#pragma unroll
  for (int fj = 0; fj < 4; ++fj) {
    int gc = bn * 128 + wn * 64 + fj * 16 + l15;
    float bvv = bias[permcol(gc)];
#pragma unroll
    for (int fi = 0; fi < 4; ++fi) {
      int gr0 = bm * 128 + wm * 64 + fi * 16 + lq * 4;
#pragma unroll
      for (int r = 0; r < 4; ++r)
        C[(size_t)(gr0 + r) * 4096 + gc] = f2bf(acc[fi][fj][r] + bvv);
    }
  }
}

// -------- fused 2-layer persistent scan --------
// 256 blocks: blk<128 = layer1 (K=1024, WhT1), blk>=128 = layer2 (K=2048, [Wx2;Wh2]).
// DEEP RINGS: hpub1/hpub2 = 64 slots x 64KB each (slot = t & 63). Within a 64-step
// epoch every ring address is written exactly once (sc0/sc1 write-through, L3-fresh),
// so consumers use PLAIN CACHED loads (co-XCD blocks share the L2 fill). One
// acquire-fence per 64 steps (epoch boundary) invalidates L1/L2 before addresses
// are reused. Flags stay uncached (sc0/sc1 polled).
template <int LAYER>
__device__ __forceinline__ void scan_body(
    f32x4* partv, float* out_stage, u16* h_stage, int blk2,
    const u16* __restrict__ xproj, const u16* __restrict__ Wt,
    const float* __restrict__ bias2, const int* __restrict__ lengths,
    u64* hpub1, u64* hpub2, int* flags,
    float* __restrict__ outp, float* __restrict__ csf, float* __restrict__ hsf) {
  const int tid = threadIdx.x;
  const int lane = tid & 63, w = tid >> 6;
  const int l15 = lane & 15, q = lane >> 4;
  const int b = (w & 1) * 16 + l15;
  const int u_local = (w >> 1) * 4 + q;
  const int len = lengths[b];

  constexpr int NKS = LAYER ? 16 : 8;
  constexpr int KSTRIDE = LAYER ? 2048 : 1024;
  const int wk = w * (LAYER ? 512 : 256);

  short8 afr[2][NKS];
#pragma unroll
  for (int tt = 0; tt < 2; ++tt)
#pragma unroll
    for (int ks = 0; ks < NKS; ++ks)
      afr[tt][ks] = *(const short8*)(Wt + (size_t)(blk2 * 32 + tt * 16 + l15) * KSTRIDE +
                                     wk + ks * 32 + q * 8);

  float bg0 = 0.f, bg1 = 0.f, bg2 = 0.f, bg3 = 0.f;
  if (LAYER) {
    bg0 = bias2[permcol(blk2 * 32 + u_local * 4 + 0)];
    bg1 = bias2[permcol(blk2 * 32 + u_local * 4 + 1)];
    bg2 = bias2[permcol(blk2 * 32 + u_local * 4 + 2)];
    bg3 = bias2[permcol(blk2 * 32 + u_local * 4 + 3)];
  }

  f32x4 acc[2][2];
#pragma unroll
  for (int tt = 0; tt < 2; ++tt)
#pragma unroll
    for (int bc = 0; bc < 2; ++bc) acc[tt][bc] = (f32x4){0.f, 0.f, 0.f, 0.f};
  float c = 0.f, h = 0.f;

  for (int t = 0; t < 256; ++t) {
    u64 xp = 0;
    if (!LAYER)
      xp = *(const u64*)(xproj + ((size_t)b * 256 + t) * 4096 + blk2 * 32 + u_local * 4);

    // ---- wave0: poll flags (uncached); epoch-boundary acquire fence ----
    if (w == 0) {
      const int n1 = LAYER ? t + 1 : t;     // flag1 threshold (peer h1 / out1(t))
      const int n2 = LAYER ? t : t - 63;    // flag2 threshold (peer h2 / slot reuse)
      if (n1 > 0 || n2 > 0) {
        const int thr = (lane < 32) ? n1 : n2;
        const u32x4* fp = (const u32x4*)flags + lane;
        while (1) {
          u32x4 fv;
          asm volatile("global_load_dwordx4 %0, %1, off sc0 sc1"
                       : "=v"(fv) : "v"(fp) : "memory");
          asm volatile("s_waitcnt vmcnt(0)" ::: "memory");
          bool ok = (int)fv[0] >= thr && (int)fv[1] >= thr &&
                    (int)fv[2] >= thr && (int)fv[3] >= thr;
          if (__all(ok)) break;
          __builtin_amdgcn_s_sleep(1);
        }
      }
      if ((t & 63) == 0)  // once per epoch: invalidate L1+L2 before slot reuse
        __builtin_amdgcn_fence(__ATOMIC_ACQUIRE, "agent");
    }
    __syncthreads();  // BP: flags satisfied (+ caches clean at epoch start)

    // ---- load h fragments (plain cached loads), MFMA ----
    if (!LAYER) {
      if (t > 0) {
        const char* hp = (const char*)(hpub1 + (size_t)((t - 1) & 63) * 8192);
        short8 bfv[16];
#pragma unroll
        for (int i = 0; i < 16; ++i) {
          const int ks = i >> 1, bc = i & 1;
          bfv[i] = *(const short8*)(hp + (((w * 32 + ks * 4 + q) * 32 + bc * 16 + l15) << 4));
        }
#pragma unroll
        for (int i = 0; i < 16; ++i) {
          const int ks = i >> 1, bc = i & 1;
          acc[0][bc] = MFMA16(afr[0][ks], bfv[i], acc[0][bc]);
          acc[1][bc] = MFMA16(afr[1][ks], bfv[i], acc[1][bc]);
        }
      }
    } else {
      const char* hp;
      int kb;
      if (w < 2) { hp = (const char*)(hpub1 + (size_t)(t & 63) * 8192); kb = w * 64; }
      else       { hp = (const char*)(hpub2 + (size_t)((t - 1) & 63) * 8192); kb = (w - 2) * 64; }
      if (w < 2 || t > 0) {
#pragma unroll
        for (int g = 0; g < 2; ++g) {   // 2 groups of 16 frags (VGPR cap)
          short8 bfv[16];
#pragma unroll
          for (int i = 0; i < 16; ++i) {
            const int ks = g * 8 + (i >> 1), bc = i & 1;
            bfv[i] = *(const short8*)(hp + (((kb + ks * 4 + q) * 32 + bc * 16 + l15) << 4));
          }
#pragma unroll
          for (int i = 0; i < 16; ++i) {
            const int ks = g * 8 + (i >> 1), bc = i & 1;
            acc[0][bc] = MFMA16(afr[0][ks], bfv[i], acc[0][bc]);
            acc[1][bc] = MFMA16(afr[1][ks], bfv[i], acc[1][bc]);
          }
        }
      }
    }

    // ---- cross-wave K reduction ----
#pragma unroll
    for (int tt = 0; tt < 2; ++tt)
#pragma unroll
      for (int bc = 0; bc < 2; ++bc) {
        partv[(w * 4 + tt * 2 + bc) * 64 + lane] = acc[tt][bc];
        acc[tt][bc] = (f32x4){0.f, 0.f, 0.f, 0.f};
      }
    __syncthreads();  // B1
    f32x4 s = (f32x4){0.f, 0.f, 0.f, 0.f};
#pragma unroll
    for (int w2 = 0; w2 < 4; ++w2) s += partv[(w2 * 4 + w) * 64 + lane];

    float zi, zj, zf, zo;
    if (!LAYER) {
      zi = s[0] + bf2f((u16)(xp & 0xffffu));
      zj = s[1] + bf2f((u16)((xp >> 16) & 0xffffu));
      zf = s[2] + bf2f((u16)((xp >> 32) & 0xffffu)) + 1.f;
      zo = s[3] + bf2f((u16)(xp >> 48));
    } else {
      zi = s[0] + bg0;
      zj = s[1] + bg1;
      zf = s[2] + bg2 + 1.f;
      zo = s[3] + bg3;
    }
    float cn = sigm(zf) * c + sigm(zi) * tanh_(zj);
    float hn = sigm(zo) * tanh_(cn);
    bool mk = t < len;
    c = mk ? cn : c;
    h = mk ? hn : h;
    float ov = mk ? hn : 0.f;
    h_stage[b * 8 + u_local] = f2bf(ov);
    if (LAYER) out_stage[b * 8 + u_local] = ov;
    __syncthreads();  // B2

    // ---- publish h + flag (uncached sc0/sc1 -> L3-fresh) ----
    if (tid < 32) {
      u64* hd = LAYER ? (hpub2 + (size_t)(t & 63) * 8192)
                      : (hpub1 + (size_t)(t & 63) * 8192);
      const u64* hsrc = (const u64*)h_stage;
      u64 v0 = hsrc[tid * 2], v1 = hsrc[tid * 2 + 1];
      __hip_atomic_store(hd + (blk2 * 32 + tid) * 2, v0, __ATOMIC_RELAXED,
                         __HIP_MEMORY_SCOPE_AGENT);
      __hip_atomic_store(hd + (blk2 * 32 + tid) * 2 + 1, v1, __ATOMIC_RELAXED,
                         __HIP_MEMORY_SCOPE_AGENT);
    }
    asm volatile("s_waitcnt vmcnt(0)" ::: "memory");  // h visible before flag
    if (tid == 0)
      __hip_atomic_store(flags + LAYER * 128 + blk2, t + 1, __ATOMIC_RELAXED,
                         __HIP_MEMORY_SCOPE_AGENT);
    if (LAYER && tid < 32) {  // per-step rnnout store (layer-2 only)
      const f32x4* osrc = (const f32x4*)out_stage;
      f32x4 o0 = osrc[tid * 2], o1 = osrc[tid * 2 + 1];
      f32x4* od = (f32x4*)(outp + ((size_t)tid * 256 + t) * 1024 + blk2 * 8);
      od[0] = o0; od[1] = o1;
    }
  }
  csf[LAYER * 32768 + b * 1024 + blk2 * 8 + u_local] = c;
  hsf[LAYER * 32768 + b * 1024 + blk2 * 8 + u_local] = h;
}

__global__ __launch_bounds__(256, 2) void lstm_fused(
    const u16* __restrict__ xproj, const u16* __restrict__ WhT1,
    const u16* __restrict__ WcT2, const float* __restrict__ bias2,
    const int* __restrict__ lengths, u64* hpub1, u64* hpub2, int* flags,
    float* __restrict__ outp, float* __restrict__ csf, float* __restrict__ hsf) {
  __shared__ f32x4 partv[16 * 64];
  __shared__ __align__(16) float out_stage[256];
  __shared__ __align__(16) u16 h_stage[256];
  const int blk = blockIdx.x;
  if (blk < 128)
    scan_body<0>(partv, out_stage, h_stage, blk, xproj, WhT1, bias2, lengths,
                 hpub1, hpub2, flags, outp, csf, hsf);
  else
    scan_body<1>(partv, out_stage, h_stage, blk - 128, xproj, WcT2, bias2, lengths,
                 hpub1, hpub2, flags, outp, csf, hsf);
}

// -------- workspace layout --------
// xproj 64MB | WhT1 8MB | WcT2 16MB | WxT1 8MB (dead after GEMM-1, REUSED as rings)
// rings: hpub1 64x64KB = 4MB @88MB, hpub2 4MB @92MB | flags @96MB
#define WS_XPROJ 0u
#define WS_WHT1 (64u << 20)
#define WS_WCT2 (72u << 20)
#define WS_WXT1 (88u << 20)
#define WS_HPUB1 (88u << 20)
#define WS_HPUB2 (92u << 20)
#define WS_FLAGS (96u << 20)

extern "C" void kernel_launch(void* const* d_in, const int* in_sizes, int n_in,
                              void* d_out, int out_size, void* d_ws, size_t ws_size,
                              hipStream_t stream) {
  const float* x = (const float*)d_in[0];
  const int* lengths = (const int*)d_in[1];
  const float* Wx = (const float*)d_in[2];
  const float* Wh = (const float*)d_in[3];
  const float* bias = (const float*)d_in[4];
  float* outp = (float*)d_out;

  if (ws_size < (size_t)WS_FLAGS + 4096) return;  // fail loudly (output stays poison)

  char* ws = (char*)d_ws;
  u16* xproj = (u16*)(ws + WS_XPROJ);
  u16* WhT1 = (u16*)(ws + WS_WHT1);
  u16* WcT2 = (u16*)(ws + WS_WCT2);
  u16* WxT1 = (u16*)(ws + WS_WXT1);
  u64* hpub1 = (u64*)(ws + WS_HPUB1);
  u64* hpub2 = (u64*)(ws + WS_HPUB2);
  int* flags = (int*)(ws + WS_FLAGS);

  hipMemsetAsync(flags, 0, 256 * sizeof(int), stream);
  transpose_convert<<<4096, 256, 0, stream>>>(Wx, Wh, WxT1, WhT1, WcT2);

  float* cs = outp + RN_;
  float* hs = cs + 65536;

  gemm_xproj<<<2048, 256, 0, stream>>>(x, WxT1, bias, xproj);
  lstm_fused<<<256, 256, 0, stream>>>(xproj, WhT1, WcT2, bias + 4096, lengths,
                                      hpub1, hpub2, flags, outp, cs, hs);
}

// Round 5
// 1751.940 us; speedup vs baseline: 1.8101x; 1.3998x over previous
//
#include <hip/hip_runtime.h>

typedef unsigned short u16;
typedef unsigned int u32;
typedef unsigned long long u64;
typedef __attribute__((ext_vector_type(8))) short short8;
typedef __attribute__((ext_vector_type(4))) float f32x4;
typedef __attribute__((ext_vector_type(4))) u32 u32x4;
typedef __attribute__((ext_vector_type(2))) u32 u32x2;

#define RN_ 8388608  // B*T*H
#define MFMA16(a, b, c) __builtin_amdgcn_mfma_f32_16x16x32_bf16(a, b, c, 0, 0, 0)

__device__ __forceinline__ u16 f2bf(float f) {
  union { float f; u32 u; } v; v.f = f;
  u32 r = v.u + 0x7fffu + ((v.u >> 16) & 1u);  // RNE (inputs finite)
  return (u16)(r >> 16);
}
__device__ __forceinline__ float bf2f(u16 h) {
  union { u32 u; float f; } v; v.u = ((u32)h) << 16;
  return v.f;
}
__device__ __forceinline__ u32 pk2(float a, float b) {
  return (u32)f2bf(a) | ((u32)f2bf(b) << 16);
}
// scan column ordering: R = blk*32 + u_local*4 + gate -> original g = gate*1024 + blk*8 + u_local
__device__ __forceinline__ int permcol(int R) {
  return (R & 3) * 1024 + ((R >> 5) << 3) + ((R >> 2) & 7);
}
__device__ __forceinline__ float sigm(float x) { return 1.f / (1.f + __expf(-x)); }
__device__ __forceinline__ float tanh_(float x) {
  float e = __expf(2.f * x);
  return 1.f - 2.f / (e + 1.f);
}

// -------- transpose + convert + permute: four [4096][1024] bf16 buffers --------
__global__ __launch_bounds__(256) void transpose_convert(
    const float* __restrict__ Wx, const float* __restrict__ Wh,
    u16* __restrict__ WxT1, u16* __restrict__ WxT2,
    u16* __restrict__ WhT1, u16* __restrict__ WhT2) {
  __shared__ float lds[64][65];
  const int bid = blockIdx.x, tid = threadIdx.x;
  const int sel = bid >> 10;
  const int tile = bid & 1023;
  const int kt = tile & 15, rt = tile >> 4;  // 16 k-tiles x 64 R-tiles
  const float* src;
  u16* dst;
  if (sel == 0)      { src = Wx;                       dst = WxT1; }
  else if (sel == 1) { src = Wx + (size_t)1024 * 4096; dst = WxT2; }
  else if (sel == 2) { src = Wh;                       dst = WhT1; }
  else               { src = Wh + (size_t)1024 * 4096; dst = WhT2; }
#pragma unroll
  for (int ii = 0; ii < 16; ++ii) {
    int idx = ii * 256 + tid;
    int r = idx >> 6, c = idx & 63;
    int run = c >> 3, u = c & 7;
    int blkLoc = run >> 2, gate = run & 3;
    int g = gate * 1024 + (rt * 2 + blkLoc) * 8 + u;
    lds[r][blkLoc * 32 + u * 4 + gate] = src[(size_t)(kt * 64 + r) * 4096 + g];
  }
  __syncthreads();
#pragma unroll
  for (int ii = 0; ii < 16; ++ii) {
    int idx = ii * 256 + tid;
    int rw = idx >> 6, cw = idx & 63;
    dst[(size_t)(rt * 64 + rw) * 1024 + kt * 64 + cw] = f2bf(lds[cw][rw]);
  }
}

// -------- chunked GEMM group (persistent): 128 blocks, 16 chunks of 512 rows --------
// IS2=0: A = x (f32, rows remapped b*256+t), out -> xp1ring, gate: ring reuse vs scan1.
// IS2=1: A = out1t (bf16, uncached), out -> xp2ring, gate: scan1 done chunk + scan2 reuse.
// C rows are t-major (r = t*32+b), cols permuted; bias added here.
template <int IS2>
__device__ void gemm_grp(char* smem, int gb,
    const float* __restrict__ Af32, const u16* __restrict__ Abf,
    const u16* __restrict__ Bt, const float* __restrict__ bias,
    u16* __restrict__ Cring, const int* flags, int* gdone) {
  u16* As = (u16*)smem;
  u16* Bs = (u16*)(smem + 16384);
  const int tid = threadIdx.x;
  const int lane = tid & 63, w = tid >> 6;
  const int wm = w >> 1, wn = w & 1;
  const int l15 = lane & 15, lq = lane >> 4;
  const int srow = tid >> 2, qd = tid & 3;
  const int mg = gb >> 5, ng = gb & 31;
  const u32 rsw = (u32)((l15 & 7) << 4);

  for (int c = 0; c < 16; ++c) {
    // ---- gate ----
    if (w == 0) {
      const int thrA = IS2 ? 16 * (c + 1) : 16 * c - 48;  // scan1 flags
      const int thrB = 16 * c - 48;                        // scan2 flags (reuse)
      while (1) {
        bool ok = true;
        if (lane < 32) {
          u32x4 fv;
          const u32x4* fp = (const u32x4*)flags + lane;
          asm volatile("global_load_dwordx4 %0, %1, off sc0 sc1"
                       : "=v"(fv) : "v"(fp) : "memory");
          asm volatile("s_waitcnt vmcnt(0)" ::: "memory");
          ok = (int)fv[0] >= thrA && (int)fv[1] >= thrA &&
               (int)fv[2] >= thrA && (int)fv[3] >= thrA;
        } else if (IS2) {
          u32x4 fv;
          const u32x4* fp = (const u32x4*)(flags + 128) + (lane - 32);
          asm volatile("global_load_dwordx4 %0, %1, off sc0 sc1"
                       : "=v"(fv) : "v"(fp) : "memory");
          asm volatile("s_waitcnt vmcnt(0)" ::: "memory");
          ok = (int)fv[0] >= thrB && (int)fv[1] >= thrB &&
               (int)fv[2] >= thrB && (int)fv[3] >= thrB;
        }
        if (__all(ok)) break;
        __builtin_amdgcn_s_sleep(8);
      }
    }
    __syncthreads();

    f32x4 acc[4][4];
#pragma unroll
    for (int i = 0; i < 4; ++i)
#pragma unroll
      for (int j = 0; j < 4; ++j) acc[i][j] = (f32x4){0.f, 0.f, 0.f, 0.f};

    for (int kt = 0; kt < 16; ++kt) {
      u32x4 aw[2][2], bv[2][2];
#pragma unroll
      for (int rr = 0; rr < 2; ++rr) {
        int row = rr * 64 + srow;
        const u32x4* bp = (const u32x4*)(Bt + (size_t)(ng * 128 + row) * 1024 + kt * 64 + qd * 16);
        bv[rr][0] = bp[0]; bv[rr][1] = bp[1];
        int rg = 512 * c + mg * 128 + row;
        if (IS2) {
          const u16* ap = Abf + (size_t)rg * 1024 + kt * 64 + qd * 16;
          asm volatile("global_load_dwordx4 %0, %1, off sc0 sc1"
                       : "=v"(aw[rr][0]) : "v"(ap) : "memory");
          asm volatile("global_load_dwordx4 %0, %1, off sc0 sc1"
                       : "=v"(aw[rr][1]) : "v"(ap + 8) : "memory");
        } else {
          const f32x4* ap = (const f32x4*)(Af32 +
              ((size_t)(rg & 31) * 256 + (rg >> 5)) * 1024 + kt * 64 + qd * 16);
          f32x4 a0 = ap[0], a1 = ap[1], a2 = ap[2], a3 = ap[3];
          aw[rr][0][0] = pk2(a0[0], a0[1]); aw[rr][0][1] = pk2(a0[2], a0[3]);
          aw[rr][0][2] = pk2(a1[0], a1[1]); aw[rr][0][3] = pk2(a1[2], a1[3]);
          aw[rr][1][0] = pk2(a2[0], a2[1]); aw[rr][1][1] = pk2(a2[2], a2[3]);
          aw[rr][1][2] = pk2(a3[0], a3[1]); aw[rr][1][3] = pk2(a3[2], a3[3]);
        }
      }
      __syncthreads();  // previous MFMA reads done before overwrite
      if (IS2) {
        asm volatile("s_waitcnt vmcnt(0)" ::: "memory");  // asm loads landed
        __builtin_amdgcn_sched_barrier(0);
      }
#pragma unroll
      for (int rr = 0; rr < 2; ++rr) {
        int row = rr * 64 + srow;
        u32 sw = (u32)((row & 7) << 4);
        int base = row * 128 + qd * 32;
        *(u32x4*)((char*)As + ((base) ^ sw)) = aw[rr][0];
        *(u32x4*)((char*)As + ((base + 16) ^ sw)) = aw[rr][1];
        *(u32x4*)((char*)Bs + ((base) ^ sw)) = bv[rr][0];
        *(u32x4*)((char*)Bs + ((base + 16) ^ sw)) = bv[rr][1];
      }
      __syncthreads();
#pragma unroll
      for (int k2 = 0; k2 < 2; ++k2) {
        short8 af[4], bf[4];
#pragma unroll
        for (int f = 0; f < 4; ++f) {
          af[f] = *(const short8*)((const char*)As +
                   (((wm * 64 + f * 16 + l15) * 128 + k2 * 64 + lq * 16) ^ rsw));
          bf[f] = *(const short8*)((const char*)Bs +
                   (((wn * 64 + f * 16 + l15) * 128 + k2 * 64 + lq * 16) ^ rsw));
        }
#pragma unroll
        for (int fi = 0; fi < 4; ++fi)
#pragma unroll
          for (int fj = 0; fj < 4; ++fj)
            acc[fi][fj] = MFMA16(af[fi], bf[fj], acc[fi][fj]);
      }
    }
    // ---- epilogue: +bias, store bf16 to ring slot c&3 (uncached) ----
#pragma unroll
    for (int fj = 0; fj < 4; ++fj) {
      int gc = ng * 128 + wn * 64 + fj * 16 + l15;
      float bvv = bias[permcol(gc)];
#pragma unroll
      for (int fi = 0; fi < 4; ++fi) {
        int rr0 = (c & 3) * 512 + mg * 128 + wm * 64 + fi * 16 + lq * 4;
#pragma unroll
        for (int r = 0; r < 4; ++r) {
          u32 vv = (u32)f2bf(acc[fi][fj][r] + bvv);
          const u16* cp = Cring + (size_t)(rr0 + r) * 4096 + gc;
          asm volatile("global_store_short %0, %1, off sc0 sc1"
                       :: "v"(cp), "v"(vv) : "memory");
        }
      }
    }
    asm volatile("s_waitcnt vmcnt(0)" ::: "memory");  // stores visible before count
    __syncthreads();
    if (tid == 0)
      __hip_atomic_fetch_add(gdone + c, 1, __ATOMIC_RELAXED, __HIP_MEMORY_SCOPE_AGENT);
  }
}

// -------- scan group (persistent): 128 blocks, 8 units each, K=1024 --------
// L=0: xp from xp1ring, publishes hpub1 + out1t (bf16 t-major), flag1.
// L=1: xp from xp2ring, publishes hpub2, flag2, writes rnnout + finals.
// hpub depth 4 (slot t&3); gate peers>=t makes reuse safe. All scan h/xp I/O uncached.
template <int L>
__device__ void scan_grp(char* smem, int blk2,
    const u16* __restrict__ xpring, const u16* __restrict__ Wt,
    const int* __restrict__ lengths, u64* hpub, u16* out1t,
    int* flags, const int* gdone,
    float* __restrict__ outp, float* __restrict__ csf, float* __restrict__ hsf) {
  f32x4* partv = (f32x4*)smem;                   // 16KB
  u16* h_stage = (u16*)(smem + 16384);           // 512B
  float* out_stage = (float*)(smem + 17408);     // 1KB (L=1)
  const int tid = threadIdx.x;
  const int lane = tid & 63, w = tid >> 6;
  const int l15 = lane & 15, q = lane >> 4;
  const int b = (w & 1) * 16 + l15;
  const int u_local = (w >> 1) * 4 + q;
  const int len = lengths[b];
  int* flags_self = flags + L * 128;

  short8 afr[2][8];
#pragma unroll
  for (int tt = 0; tt < 2; ++tt)
#pragma unroll
    for (int ks = 0; ks < 8; ++ks)
      afr[tt][ks] = *(const short8*)(Wt + (size_t)(blk2 * 32 + tt * 16 + l15) * 1024 +
                                     w * 256 + ks * 32 + q * 8);

  f32x4 acc[2][2];
#pragma unroll
  for (int tt = 0; tt < 2; ++tt)
#pragma unroll
    for (int bc = 0; bc < 2; ++bc) acc[tt][bc] = (f32x4){0.f, 0.f, 0.f, 0.f};
  float c = 0.f, h = 0.f;

  for (int t = 0; t < 256; ++t) {
    // ---- gate: peers >= t, and xp chunk ready ----
    if (w == 0) {
      const int cidx = t >> 4;
      while (1) {
        bool ok = true;
        if (lane < 32) {
          u32x4 fv;
          const u32x4* fp = (const u32x4*)flags_self + lane;
          asm volatile("global_load_dwordx4 %0, %1, off sc0 sc1"
                       : "=v"(fv) : "v"(fp) : "memory");
          asm volatile("s_waitcnt vmcnt(0)" ::: "memory");
          ok = (int)fv[0] >= t && (int)fv[1] >= t && (int)fv[2] >= t && (int)fv[3] >= t;
        } else if (lane == 32) {
          u32 cd;
          const int* gp = gdone + cidx;
          asm volatile("global_load_dword %0, %1, off sc0 sc1"
                       : "=v"(cd) : "v"(gp) : "memory");
          asm volatile("s_waitcnt vmcnt(0)" ::: "memory");
          ok = (int)cd >= 128;
        }
        if (__all(ok)) break;
        __builtin_amdgcn_s_sleep(1);
      }
    }
    __syncthreads();  // BP

    // ---- xp load (uncached; ring slot (t>>4)&3, row (t&15)*32+b) ----
    const u16* xa = xpring + ((size_t)((t >> 4) & 3) * 512 + (t & 15) * 32 + b) * 4096 +
                    blk2 * 32 + u_local * 4;
    u32x2 xpv;
    asm volatile("global_load_dwordx2 %0, %1, off sc0 sc1"
                 : "=v"(xpv) : "v"(xa) : "memory");

    // ---- h fragments + MFMA ----
    if (t > 0) {
      const char* hp = (const char*)hpub + (size_t)((t - 1) & 3) * 65536;
      short8 bfv[16];
#pragma unroll
      for (int i = 0; i < 16; ++i) {
        const int ks = i >> 1, bc = i & 1;
        const char* p = hp + (((w * 32 + ks * 4 + q) * 32 + bc * 16 + l15) << 4);
        asm volatile("global_load_dwordx4 %0, %1, off sc0 sc1"
                     : "=v"(bfv[i]) : "v"(p) : "memory");
      }
      asm volatile("s_waitcnt vmcnt(0)" ::: "memory");
      __builtin_amdgcn_sched_barrier(0);
#pragma unroll
      for (int i = 0; i < 16; ++i) {
        const int ks = i >> 1, bc = i & 1;
        acc[0][bc] = MFMA16(afr[0][ks], bfv[i], acc[0][bc]);
        acc[1][bc] = MFMA16(afr[1][ks], bfv[i], acc[1][bc]);
      }
    } else {
      asm volatile("s_waitcnt vmcnt(0)" ::: "memory");
      __builtin_amdgcn_sched_barrier(0);
    }

    // ---- cross-wave K reduction ----
#pragma unroll
    for (int tt = 0; tt < 2; ++tt)
#pragma unroll
      for (int bc = 0; bc < 2; ++bc) {
        partv[(w * 4 + tt * 2 + bc) * 64 + lane] = acc[tt][bc];
        acc[tt][bc] = (f32x4){0.f, 0.f, 0.f, 0.f};
      }
    __syncthreads();  // B1
    f32x4 s = (f32x4){0.f, 0.f, 0.f, 0.f};
#pragma unroll
    for (int w2 = 0; w2 < 4; ++w2) s += partv[(w2 * 4 + w) * 64 + lane];

    float zi = s[0] + bf2f((u16)(xpv[0] & 0xffffu));
    float zj = s[1] + bf2f((u16)(xpv[0] >> 16));
    float zf = s[2] + bf2f((u16)(xpv[1] & 0xffffu)) + 1.f;  // FORGET_BIAS
    float zo = s[3] + bf2f((u16)(xpv[1] >> 16));
    float cn = sigm(zf) * c + sigm(zi) * tanh_(zj);
    float hn = sigm(zo) * tanh_(cn);
    bool mk = t < len;
    c = mk ? cn : c;
    h = mk ? hn : h;
    float ov = mk ? hn : 0.f;
    h_stage[b * 8 + u_local] = f2bf(ov);
    if (L) out_stage[b * 8 + u_local] = ov;
    __syncthreads();  // B2

    // ---- publish (uncached), drain, flag ----
    if (tid < 32) {
      u64* hd = hpub + (size_t)(t & 3) * 8192;
      const u64* hsrc = (const u64*)h_stage;
      u64 v0 = hsrc[tid * 2], v1 = hsrc[tid * 2 + 1];
      __hip_atomic_store(hd + (blk2 * 32 + tid) * 2, v0, __ATOMIC_RELAXED,
                         __HIP_MEMORY_SCOPE_AGENT);
      __hip_atomic_store(hd + (blk2 * 32 + tid) * 2 + 1, v1, __ATOMIC_RELAXED,
                         __HIP_MEMORY_SCOPE_AGENT);
      if (!L) {  // out1 for GEMM2, t-major rows
        u64* od = (u64*)(out1t + ((size_t)t * 32 + tid) * 1024 + blk2 * 8);
        __hip_atomic_store(od, v0, __ATOMIC_RELAXED, __HIP_MEMORY_SCOPE_AGENT);
        __hip_atomic_store(od + 1, v1, __ATOMIC_RELAXED, __HIP_MEMORY_SCOPE_AGENT);
      }
    }
    asm volatile("s_waitcnt vmcnt(0)" ::: "memory");  // visible before flag
    if (tid == 0)
      __hip_atomic_store(flags_self + blk2, t + 1, __ATOMIC_RELAXED,
                         __HIP_MEMORY_SCOPE_AGENT);
    if (L && tid < 32) {  // rnnout rows (b=tid, t)
      const f32x4* osrc = (const f32x4*)out_stage;
      f32x4 o0 = osrc[tid * 2], o1 = osrc[tid * 2 + 1];
      f32x4* od = (f32x4*)(outp + ((size_t)tid * 256 + t) * 1024 + blk2 * 8);
      od[0] = o0; od[1] = o1;
    }
  }
  csf[L * 32768 + b * 1024 + blk2 * 8 + u_local] = c;
  hsf[L * 32768 + b * 1024 + blk2 * 8 + u_local] = h;
}

// -------- 4-group persistent pipeline: G1 | scan1 | G2 | scan2, 128 blocks each --------
__global__ __launch_bounds__(256, 2) void lstm_pipe(
    const float* __restrict__ x, const int* __restrict__ lengths,
    const float* __restrict__ bias,
    const u16* __restrict__ WxT1, const u16* __restrict__ WxT2,
    const u16* __restrict__ WhT1, const u16* __restrict__ WhT2,
    u16* xp1ring, u16* xp2ring, u16* out1t,
    u64* hpub1, u64* hpub2, int* flags, float* outp) {
  __shared__ __align__(16) char smem[32768];
  int* g1done = flags + 256;
  int* g2done = flags + 272;
  const int g = blockIdx.x >> 7, gb = blockIdx.x & 127;
  float* csf = outp + RN_;
  float* hsf = csf + 65536;
  if (g == 0)
    gemm_grp<0>(smem, gb, x, nullptr, WxT1, bias, xp1ring, flags, g1done);
  else if (g == 1)
    scan_grp<0>(smem, gb, xp1ring, WhT1, lengths, hpub1, out1t, flags, g1done,
                outp, csf, hsf);
  else if (g == 2)
    gemm_grp<1>(smem, gb, nullptr, out1t, WxT2, bias + 4096, xp2ring, flags, g2done);
  else
    scan_grp<1>(smem, gb, xp2ring, WhT2, lengths, hpub2, nullptr, flags, g2done,
                outp, csf, hsf);
}

// -------- workspace layout (fits proven 96.5MB budget; total ~80.6MB) --------
#define WS_WXT1 0u
#define WS_WXT2 (8u << 20)
#define WS_WHT1 (16u << 20)
#define WS_WHT2 (24u << 20)
#define WS_XP1 (32u << 20)    // 4 slots x 512 rows x 4096 x 2B = 16MB
#define WS_XP2 (48u << 20)    // 16MB
#define WS_OUT1 (64u << 20)   // 8192 x 1024 x 2B = 16MB
#define WS_HPUB1 (80u << 20)              // 4 x 64KB
#define WS_HPUB2 ((80u << 20) + (256u << 10))
#define WS_FLAGS ((80u << 20) + (512u << 10))  // 256 flags + 16 + 16 counters

extern "C" void kernel_launch(void* const* d_in, const int* in_sizes, int n_in,
                              void* d_out, int out_size, void* d_ws, size_t ws_size,
                              hipStream_t stream) {
  const float* x = (const float*)d_in[0];
  const int* lengths = (const int*)d_in[1];
  const float* Wx = (const float*)d_in[2];
  const float* Wh = (const float*)d_in[3];
  const float* bias = (const float*)d_in[4];
  float* outp = (float*)d_out;

  if (ws_size < (size_t)WS_FLAGS + 4096) return;  // fail loudly (output stays poison)

  char* ws = (char*)d_ws;
  u16* WxT1 = (u16*)(ws + WS_WXT1);
  u16* WxT2 = (u16*)(ws + WS_WXT2);
  u16* WhT1 = (u16*)(ws + WS_WHT1);
  u16* WhT2 = (u16*)(ws + WS_WHT2);
  u16* xp1ring = (u16*)(ws + WS_XP1);
  u16* xp2ring = (u16*)(ws + WS_XP2);
  u16* out1t = (u16*)(ws + WS_OUT1);
  u64* hpub1 = (u64*)(ws + WS_HPUB1);
  u64* hpub2 = (u64*)(ws + WS_HPUB2);
  int* flags = (int*)(ws + WS_FLAGS);

  hipMemsetAsync(flags, 0, 2048, stream);
  transpose_convert<<<4096, 256, 0, stream>>>(Wx, Wh, WxT1, WxT2, WhT1, WhT2);
  lstm_pipe<<<512, 256, 0, stream>>>(x, lengths, bias, WxT1, WxT2, WhT1, WhT2,
                                     xp1ring, xp2ring, out1t, hpub1, hpub2, flags, outp);
}